// Round 6
// baseline (1020.123 us; speedup 1.0000x reference)
//
#include <hip/hip_runtime.h>
#include <cstddef>

#define NN 100000
#define NE 400000
#define NG 256
#define HIDC 256
#define EPSN 1e-5f

typedef unsigned short bfu;  // bf16 bits
using short8 = __attribute__((ext_vector_type(8))) short;
using f32x4  = __attribute__((ext_vector_type(4))) float;
using f32x2  = __attribute__((ext_vector_type(2))) float;

#if defined(__has_builtin)
#if __has_builtin(__builtin_amdgcn_cvt_pk_fp8_f32) && __has_builtin(__builtin_amdgcn_cvt_pk_f32_fp8)
#define HWFP8 1
#endif
#endif

__device__ __forceinline__ float bf2f(bfu b) {
    union { unsigned int u; float f; } v; v.u = ((unsigned int)b) << 16; return v.f;
}
__device__ __forceinline__ bfu f2bf(float f) {
    union { float f; unsigned int u; } v; v.f = f;
    unsigned int r = v.u + 0x7FFFu + ((v.u >> 16) & 1u);
    return (bfu)(r >> 16);
}
// ---- fp8 e4m3 software fallback ----
__device__ __forceinline__ float e4m3f_sw(unsigned char b) {
    unsigned s = ((unsigned)(b & 0x80u)) << 24;
    unsigned E = (b >> 3) & 15u, M = b & 7u;
    union { unsigned x; float f; } o;
    if (E == 0) { o.f = (float)M * 0.001953125f; o.x |= s; }
    else o.x = s | ((E + 120u) << 23) | (M << 20);
    return o.f;
}
__device__ __forceinline__ unsigned char f2e4m3_sw(float f) {
    union { float f; unsigned u; } v; v.f = f;
    unsigned s = (v.u >> 24) & 0x80u;
    float a = fabsf(f);
    if (!(a < 448.f)) return (unsigned char)(s | 0x7Eu);
    if (a < 0.0009765625f) return (unsigned char)s;
    if (a < 0.015625f) {
        int m = (int)(a * 512.f + 0.5f);
        if (m >= 8) return (unsigned char)(s | 0x08u);
        return (unsigned char)(s | (unsigned)m);
    }
    unsigned u = v.u;
    unsigned r = u + 0x7FFFFu + ((u >> 20) & 1u);
    int E = (int)((r >> 23) & 255u) - 127 + 7;
    unsigned M = (r >> 20) & 7u;
    if (E >= 16) return (unsigned char)(s | 0x7Eu);
    if (E <= 0) {
        int m = (int)(a * 512.f + 0.5f); if (m > 7) m = 7;
        return (unsigned char)(s | (unsigned)m);
    }
    return (unsigned char)(s | ((unsigned)E << 3) | M);
}
// ---- 4-wide fp8 pack/unpack (HW when available) ----
__device__ __forceinline__ unsigned int fp8enc4(float a, float b, float c, float d) {
#ifdef HWFP8
    int lo = __builtin_amdgcn_cvt_pk_fp8_f32(a, b, 0, false);
    int hi = __builtin_amdgcn_cvt_pk_fp8_f32(c, d, 0, false);
    return (unsigned int)((lo & 0xFFFF) | (hi << 16));
#else
    return (unsigned)f2e4m3_sw(a) | ((unsigned)f2e4m3_sw(b) << 8) |
           ((unsigned)f2e4m3_sw(c) << 16) | ((unsigned)f2e4m3_sw(d) << 24);
#endif
}
__device__ __forceinline__ float4 fp8dec4(unsigned int u) {
#ifdef HWFP8
    f32x2 lo = __builtin_amdgcn_cvt_pk_f32_fp8((int)u, false);
    f32x2 hi = __builtin_amdgcn_cvt_pk_f32_fp8((int)u, true);
    return make_float4(lo[0], lo[1], hi[0], hi[1]);
#else
    return make_float4(e4m3f_sw(u & 255u), e4m3f_sw((u >> 8) & 255u),
                       e4m3f_sw((u >> 16) & 255u), e4m3f_sw((u >> 24) & 255u));
#endif
}
__device__ __forceinline__ float4 ld4(const void* p, size_t i, int bf) {
    if (bf) {
        ushort4 u = *(const ushort4*)((const bfu*)p + i);
        return make_float4(bf2f(u.x), bf2f(u.y), bf2f(u.z), bf2f(u.w));
    }
    return *(const float4*)((const float*)p + i);
}
__device__ __forceinline__ float ld1(const void* p, size_t i, int bf) {
    return bf ? bf2f(((const bfu*)p)[i]) : ((const float*)p)[i];
}
__device__ __forceinline__ void st1(void* p, size_t i, float v, int bf) {
    if (bf) ((bfu*)p)[i] = f2bf(v); else ((float*)p)[i] = v;
}

// ---------------- dtype detect ----------------
__global__ void k_dt2(const unsigned int* __restrict__ g, int* __restrict__ flag) {
    if (threadIdx.x == 0)
        flag[0] = (g[0] == 0x3F800000u) ? 0 : 1;
}

// ---------------- graph starts (batch sorted) ----------------
__global__ void k_st2(const int* __restrict__ batch, int* __restrict__ starts) {
    int g = threadIdx.x;
    if (g > NG) return;
    if (g == NG) { starts[NG] = NN; return; }
    int lo = 0, hi = NN;
    while (lo < hi) { int mid = (lo + hi) >> 1; if (batch[mid] < g) lo = mid + 1; else hi = mid; }
    starts[g] = lo;
}

__global__ void k_zi(int* __restrict__ p, int n) {
    int i = blockIdx.x * blockDim.x + threadIdx.x;
    if (i < n) p[i] = 0;
}

// ---------------- CSR build ----------------
__global__ void k_cnt(const int* __restrict__ ei, int* __restrict__ deg) {
    int e = blockIdx.x * blockDim.x + threadIdx.x;
    if (e >= NE) return;
    int d = ei[NE + e];
    if ((unsigned)d < (unsigned)NN) atomicAdd(&deg[d], 1);
}
__global__ void k_sc1(const int* __restrict__ deg, int* __restrict__ rowp,
                      int* __restrict__ part) {
    __shared__ int sh[256];
    int b = blockIdx.x, t = threadIdx.x;
    int i = b * 256 + t;
    int v = (i < NN) ? deg[i] : 0;
    sh[t] = v; __syncthreads();
    for (int off = 1; off < 256; off <<= 1) {
        int add = (t >= off) ? sh[t - off] : 0;
        __syncthreads();
        sh[t] += add; __syncthreads();
    }
    if (i < NN) rowp[i] = sh[t] - v;
    if (t == 255) part[b] = sh[255];
}
__global__ void k_sc2(int* __restrict__ part, int nb) {
    if (threadIdx.x != 0) return;
    int run = 0;
    for (int b = 0; b < nb; ++b) { int t = part[b]; part[b] = run; run += t; }
}
__global__ void k_sc3(int* __restrict__ rowp, const int* __restrict__ part) {
    int i = blockIdx.x * blockDim.x + threadIdx.x;
    if (i < NN) rowp[i] += part[blockIdx.x];
    if (i == 0) rowp[NN] = NE;
}
__global__ void k_cpi(const int* __restrict__ a, int* __restrict__ b, int n) {
    int i = blockIdx.x * blockDim.x + threadIdx.x;
    if (i < n) b[i] = a[i];
}
__global__ void k_fil(const int* __restrict__ ei, int* __restrict__ cursor,
                      int* __restrict__ csrc, int* __restrict__ ceid) {
    int e = blockIdx.x * blockDim.x + threadIdx.x;
    if (e >= NE) return;
    int s = ei[e], d = ei[NE + e];
    if ((unsigned)d >= (unsigned)NN) return;
    int pos = atomicAdd(&cursor[d], 1);
    csrc[pos] = ((unsigned)s < (unsigned)NN) ? s : 0;
    ceid[pos] = e;
}

// ---------------- Weff = Wemb @ W1 (4x256) f32, beff = bemb @ W1 + b1 f32 ------
__global__ void k_wef(const void* __restrict__ Wemb, const void* __restrict__ bemb,
                      const void* __restrict__ W1, const void* __restrict__ b1,
                      float* __restrict__ weff, float* __restrict__ beff,
                      const int* __restrict__ dtf) {
    int bf = *dtf;
    int j = blockIdx.x;
    int n = threadIdx.x;
    float acc = 0.f;
    if (j < 4) {
        for (int k = 0; k < HIDC; ++k)
            acc += ld1(Wemb, (size_t)j * HIDC + k, bf) * ld1(W1, (size_t)k * HIDC + n, bf);
        weff[j * HIDC + n] = acc;
    } else {
        for (int k = 0; k < HIDC; ++k)
            acc += ld1(bemb, k, bf) * ld1(W1, (size_t)k * HIDC + n, bf);
        beff[n] = acc + ld1(b1, n, bf);
    }
}

// ---------------- full-range CSR gather: agg_bf16[n] = sum relu(h[src]+e8) ------
__global__ void k_gat3(const bfu* __restrict__ h, const unsigned char* __restrict__ e8,
                       const int* __restrict__ rowp, const int* __restrict__ csrc,
                       bfu* __restrict__ agg) {
    int tid = blockIdx.x * blockDim.x + threadIdx.x;
    if (tid >= NN * 64) return;
    int n = tid >> 6, q = (tid & 63) << 2;
    int s0 = rowp[n], s1 = rowp[n + 1];
    float4 a = make_float4(0.f, 0.f, 0.f, 0.f);
    for (int i = s0; i < s1; ++i) {
        int src = csrc[i];
        ushort4 hu = *(const ushort4*)(h + (size_t)src * HIDC + q);
        unsigned int eu = *(const unsigned int*)(e8 + (size_t)i * HIDC + q);
        float4 ev = fp8dec4(eu);
        a.x += fmaxf(bf2f(hu.x) + ev.x, 0.f);
        a.y += fmaxf(bf2f(hu.y) + ev.y, 0.f);
        a.z += fmaxf(bf2f(hu.z) + ev.z, 0.f);
        a.w += fmaxf(bf2f(hu.w) + ev.w, 0.f);
    }
    ushort4 o; o.x = f2bf(a.x); o.y = f2bf(a.y); o.z = f2bf(a.z); o.w = f2bf(a.w);
    *(ushort4*)(agg + (size_t)n * HIDC + q) = o;
}

// ---------------- weight transpose to MFMA-fragment-swizzled bf16 ----------------
__global__ void k_wtr(const void* __restrict__ W, long wOff, bfu* __restrict__ Wt,
                      const int* __restrict__ dtf) {
    int o = blockIdx.x * blockDim.x + threadIdx.x;
    if (o >= HIDC * HIDC) return;
    int blk = o >> 9, pos = o & 511;
    int w = blk >> 5, rem = blk & 31;
    int t = rem >> 3, kb = rem & 7;
    int pr = pos >> 3, j = pos & 7;
    int lr = pr >> 2, lq = pr & 3;
    int n = w * 64 + t * 16 + lr;
    int k = kb * 32 + lq * 8 + j;
    Wt[o] = f2bf(ld1(W, (size_t)wOff + (size_t)k * HIDC + n, *dtf));
}

// ---------------- node embedding gather ----------------
__global__ void k_emb(const int* __restrict__ x, const void* __restrict__ W,
                      bfu* __restrict__ h, const int* __restrict__ dtf) {
    int tid = blockIdx.x * blockDim.x + threadIdx.x;
    if (tid >= NN * 64) return;
    int bf = *dtf;
    int n = tid >> 6, q = (tid & 63) << 2;
    int xv = x[n]; if ((unsigned)xv >= 8u) xv = 0;
    float4 v = ld4(W, (size_t)xv * HIDC + q, bf);
    ushort4 o; o.x = f2bf(v.x); o.y = f2bf(v.y); o.z = f2bf(v.z); o.w = f2bf(v.w);
    *(ushort4*)(h + (size_t)n * HIDC + q) = o;
}

// ---------------- edge MLP: e8 = fp8[(relu(attr@weff+beff) @ W2 + b2) * scale] --
// v5: v4 structure, but DENSE output stores: gdst[tid] / gdst[512+tid] so each
// wave instruction covers 1024 B contiguous and every 128 B line is written by
// exactly ONE instruction. v4's tid*32 split stores left half-line holes per
// instruction -> line fills (FETCH +47 MB) and 2x WRITE (200 MB observed).
__global__ __launch_bounds__(512, 8)
void k_me(const void* __restrict__ attrs,
          const float* __restrict__ weff, const float* __restrict__ beff,
          const bfu* __restrict__ Wt, const void* __restrict__ bias,
          const void* __restrict__ scalep,
          unsigned char* __restrict__ C,
          const int* __restrict__ dtf, const int* __restrict__ eidx) {
    __shared__ bfu As[4][64 * 32];   // 16 KB: A-tiles, then fp8 output staging
    __shared__ float wsh[1280];      // weff 4x256 | beff 256
    __shared__ float sf[64];
    const int bf = *dtf;
    const int tid = threadIdx.x;
    const int wave = tid >> 6, lane = tid & 63;
    const int lr = lane & 15, lq = lane >> 4;
    const int wr = wave >> 2, wc = wave & 3;   // row half / col quarter
    const int m0 = blockIdx.x * 64;
    const int row = tid >> 3;                  // 0..63
    const int a4 = (tid & 7) << 2;             // 0..28, 4 cols per thread

    for (int v = tid; v < 1280; v += 512)
        wsh[v] = (v < 1024) ? weff[v] : beff[v - 1024];

    float aa[4];
    {
        long er = (long)eidx[m0 + row];
        aa[0] = ld1(attrs, (size_t)er * 4 + 0, bf);
        aa[1] = ld1(attrs, (size_t)er * 4 + 1, bf);
        aa[2] = ld1(attrs, (size_t)er * 4 + 2, bf);
        aa[3] = ld1(attrs, (size_t)er * 4 + 3, bf);
    }
    if ((tid & 7) == 0)
        sf[row] = (aa[1] > 0.f) ? ld1(scalep, 0, bf) : 1.0f;
    __syncthreads();   // wsh + sf ready

    f32x4 acc[2][4] = {};
    const bfu* wb = Wt + ((size_t)wc * 32) * 512 + (size_t)(lr * 4 + lq) * 8;

    for (int h = 0; h < 2; ++h) {
        if (h) __syncthreads();   // prior MFMA reads of As complete
#pragma unroll
        for (int q = 0; q < 4; ++q) {
            const int c = h * 128 + q * 32 + a4;
            float4 bb = *(const float4*)(wsh + 1024 + c);
            float v0 = bb.x, v1 = bb.y, v2 = bb.z, v3 = bb.w;
#pragma unroll
            for (int j = 0; j < 4; ++j) {
                float4 w0 = *(const float4*)(wsh + j * 256 + c);
                v0 += aa[j] * w0.x; v1 += aa[j] * w0.y;
                v2 += aa[j] * w0.z; v3 += aa[j] * w0.w;
            }
            ushort4 o;
            o.x = f2bf(fmaxf(v0, 0.f)); o.y = f2bf(fmaxf(v1, 0.f));
            o.z = f2bf(fmaxf(v2, 0.f)); o.w = f2bf(fmaxf(v3, 0.f));
            *(ushort4*)(&As[q][row * 32 + a4]) = o;
        }
        __syncthreads();
#pragma unroll
        for (int q = 0; q < 4; ++q) {
            const int kb = h * 4 + q;
            short8 fa0 = *(const short8*)(&As[q][(wr * 32 + lr) * 32 + lq * 8]);
            short8 fa1 = *(const short8*)(&As[q][(wr * 32 + 16 + lr) * 32 + lq * 8]);
#pragma unroll
            for (int t = 0; t < 4; ++t) {
                short8 fb = *(const short8*)(wb + (size_t)(t * 8 + kb) * 512);
                acc[0][t] = __builtin_amdgcn_mfma_f32_16x16x32_bf16(fa0, fb, acc[0][t], 0, 0, 0);
                acc[1][t] = __builtin_amdgcn_mfma_f32_16x16x32_bf16(fa1, fb, acc[1][t], 0, 0, 0);
            }
        }
    }
    __syncthreads();   // all MFMA reads of As done; reuse As as output staging

    // ---- epilogue: fp8 tile -> LDS (byte writes), then coalesced global ----
    unsigned char* tile = (unsigned char*)&As[0][0];   // [64 rows][256 cols]
    float bv[4];
#pragma unroll
    for (int t = 0; t < 4; ++t)
        bv[t] = ld1(bias, (size_t)(wc * 64 + t * 16 + lr), bf);
#pragma unroll
    for (int r = 0; r < 2; ++r) {
#pragma unroll
        for (int i = 0; i < 4; ++i) {
            int rr = wr * 32 + r * 16 + lq * 4 + i;
            float rs = sf[rr];
            float ov0 = (acc[r][0][i] + bv[0]) * rs;
            float ov1 = (acc[r][1][i] + bv[1]) * rs;
            float ov2 = (acc[r][2][i] + bv[2]) * rs;
            float ov3 = (acc[r][3][i] + bv[3]) * rs;
            unsigned int pk = fp8enc4(ov0, ov1, ov2, ov3);
            int cb = rr * 256 + wc * 64 + lr;
            tile[cb]      = (unsigned char)(pk & 255u);
            tile[cb + 16] = (unsigned char)((pk >> 8) & 255u);
            tile[cb + 32] = (unsigned char)((pk >> 16) & 255u);
            tile[cb + 48] = (unsigned char)(pk >> 24);
        }
    }
    __syncthreads();
    // dense: each wave instr covers 1024 B contiguous, one instr per 128 B line
    {
        const uint4* lsrc = (const uint4*)tile;
        uint4* gdst = (uint4*)(C + (size_t)m0 * HIDC);
        gdst[tid] = lsrc[tid];
        gdst[512 + tid] = lsrc[512 + tid];
    }
}

// ---------------- fused GINE conv: h = (relu(((1+eps)h+agg)@W1+b1))@W2+b2 -------
__global__ __launch_bounds__(256)
void k_cnv(bfu* __restrict__ h, const bfu* __restrict__ agg,
           const void* __restrict__ eps, int epsIdx,
           const bfu* __restrict__ Wt1, const void* __restrict__ bias1, long b1Off,
           const bfu* __restrict__ Wt2, const void* __restrict__ bias2, long b2Off,
           const int* __restrict__ dtf) {
    __shared__ bfu Ts[8][64 * 32];   // 32 KB: Z tiles (phase 1), then T tiles (phase 2)
    const int bf = *dtf;
    const int tid = threadIdx.x;
    const int wave = tid >> 6, lane = tid & 63;
    const int lr = lane & 15, lq = lane >> 4;
    const int m0 = blockIdx.x * 64;
    const float epsv = 1.0f + ld1(eps, epsIdx, bf);
    const int row = tid >> 2;
    const int ak = (tid & 3) << 3;
    const int gmA = m0 + row;
    const bfu* wb1 = Wt1 + ((size_t)wave * 32) * 512 + (size_t)(lr * 4 + lq) * 8;
    const bfu* wb2 = Wt2 + ((size_t)wave * 32) * 512 + (size_t)(lr * 4 + lq) * 8;

    // ---- phase 0: Z = (1+eps)h + agg -> LDS ----
#pragma unroll
    for (int k0 = 0; k0 < 256; k0 += 32) {
        float hv[8] = {}, gv[8] = {};
        if (gmA < NN) {
            ushort4 h0 = *(const ushort4*)(h + (size_t)gmA * HIDC + k0 + ak);
            ushort4 h1 = *(const ushort4*)(h + (size_t)gmA * HIDC + k0 + ak + 4);
            hv[0]=bf2f(h0.x); hv[1]=bf2f(h0.y); hv[2]=bf2f(h0.z); hv[3]=bf2f(h0.w);
            hv[4]=bf2f(h1.x); hv[5]=bf2f(h1.y); hv[6]=bf2f(h1.z); hv[7]=bf2f(h1.w);
            ushort4 g0 = *(const ushort4*)(agg + (size_t)gmA * HIDC + k0 + ak);
            ushort4 g1 = *(const ushort4*)(agg + (size_t)gmA * HIDC + k0 + ak + 4);
            gv[0]=bf2f(g0.x); gv[1]=bf2f(g0.y); gv[2]=bf2f(g0.z); gv[3]=bf2f(g0.w);
            gv[4]=bf2f(g1.x); gv[5]=bf2f(g1.y); gv[6]=bf2f(g1.z); gv[7]=bf2f(g1.w);
        }
        ushort4 o0, o1;
        o0.x = f2bf(epsv * hv[0] + gv[0]); o0.y = f2bf(epsv * hv[1] + gv[1]);
        o0.z = f2bf(epsv * hv[2] + gv[2]); o0.w = f2bf(epsv * hv[3] + gv[3]);
        o1.x = f2bf(epsv * hv[4] + gv[4]); o1.y = f2bf(epsv * hv[5] + gv[5]);
        o1.z = f2bf(epsv * hv[6] + gv[6]); o1.w = f2bf(epsv * hv[7] + gv[7]);
        *(ushort4*)(&Ts[k0 >> 5][row * 32 + ak]) = o0;
        *(ushort4*)(&Ts[k0 >> 5][row * 32 + ak + 4]) = o1;
    }
    __syncthreads();

    // ---- phase 1: T = Z @ W1 ----
    f32x4 acc[4][4] = {};
#pragma unroll
    for (int kb = 0; kb < 8; ++kb) {
        short8 fa[4], fbv[4];
#pragma unroll
        for (int r = 0; r < 4; ++r)
            fa[r] = *(const short8*)(&Ts[kb][(r * 16 + lr) * 32 + lq * 8]);
#pragma unroll
        for (int t = 0; t < 4; ++t)
            fbv[t] = *(const short8*)(wb1 + (size_t)(t * 8 + kb) * 512);
#pragma unroll
        for (int r = 0; r < 4; ++r)
#pragma unroll
            for (int t = 0; t < 4; ++t)
                acc[r][t] = __builtin_amdgcn_mfma_f32_16x16x32_bf16(
                    fa[r], fbv[t], acc[r][t], 0, 0, 0);
    }
    __syncthreads();

    // ---- T = relu(acc + b1) -> Ts (overwrite), reset acc ----
    {
        float bv[4];
#pragma unroll
        for (int t = 0; t < 4; ++t)
            bv[t] = ld1(bias1, (size_t)b1Off + wave * 64 + t * 16 + lr, bf);
        const f32x4 z4 = {0.f, 0.f, 0.f, 0.f};
#pragma unroll
        for (int r = 0; r < 4; ++r) {
#pragma unroll
            for (int i = 0; i < 4; ++i) {
                int rowo = r * 16 + lq * 4 + i;
#pragma unroll
                for (int t = 0; t < 4; ++t) {
                    int kk = wave * 64 + t * 16 + lr;
                    Ts[kk >> 5][rowo * 32 + (kk & 31)] =
                        f2bf(fmaxf(acc[r][t][i] + bv[t], 0.f));
                }
            }
        }
#pragma unroll
        for (int r = 0; r < 4; ++r)
#pragma unroll
            for (int t = 0; t < 4; ++t)
                acc[r][t] = z4;
    }
    __syncthreads();

    // ---- phase 2: h = T @ W2 + b2 ----
#pragma unroll
    for (int kb = 0; kb < 8; ++kb) {
        short8 fa[4], fbv[4];
#pragma unroll
        for (int r = 0; r < 4; ++r)
            fa[r] = *(const short8*)(&Ts[kb][(r * 16 + lr) * 32 + lq * 8]);
#pragma unroll
        for (int t = 0; t < 4; ++t)
            fbv[t] = *(const short8*)(wb2 + (size_t)(t * 8 + kb) * 512);
#pragma unroll
        for (int r = 0; r < 4; ++r)
#pragma unroll
            for (int t = 0; t < 4; ++t)
                acc[r][t] = __builtin_amdgcn_mfma_f32_16x16x32_bf16(
                    fa[r], fbv[t], acc[r][t], 0, 0, 0);
    }
    float bv[4];
#pragma unroll
    for (int t = 0; t < 4; ++t)
        bv[t] = ld1(bias2, (size_t)b2Off + wave * 64 + t * 16 + lr, bf);
#pragma unroll
    for (int r = 0; r < 4; ++r) {
#pragma unroll
        for (int i = 0; i < 4; ++i) {
            int gm = m0 + r * 16 + lq * 4 + i;
            if (gm >= NN) continue;
            size_t cbase = (size_t)gm * HIDC + wave * 64 + lr;
#pragma unroll
            for (int t = 0; t < 4; ++t)
                h[cbase + t * 16] = f2bf(acc[r][t][i] + bv[t]);
        }
    }
}

// ---------------- GraphNorm stats: stage 1 (partials) + stage 2 (reduce) -------
__global__ void k_s1(const bfu* __restrict__ h, const int* __restrict__ starts,
                     float* __restrict__ psum, float* __restrict__ psq) {
    int g = blockIdx.x, c8 = blockIdx.y, c = threadIdx.x;
    int s = starts[g], t = starts[g + 1];
    int len = t - s;
    int b = s + (int)(((long)len * c8) >> 3);
    int e = s + (int)(((long)len * (c8 + 1)) >> 3);
    float sum = 0.f, sq = 0.f;
    for (int n = b; n < e; ++n) {
        float v = bf2f(h[(size_t)n * HIDC + c]);
        sum += v; sq += v * v;
    }
    psum[((size_t)g * 8 + c8) * HIDC + c] = sum;
    psq[((size_t)g * 8 + c8) * HIDC + c] = sq;
}
__global__ void k_s2(const int* __restrict__ starts,
                     const float* __restrict__ psum, const float* __restrict__ psq,
                     const void* __restrict__ alpha, long aOff,
                     float* __restrict__ gmean, float* __restrict__ gvar,
                     const int* __restrict__ dtf) {
    int g = blockIdx.x, c = threadIdx.x;
    float sum = 0.f, sq = 0.f;
#pragma unroll
    for (int j = 0; j < 8; ++j) {
        sum += psum[((size_t)g * 8 + j) * HIDC + c];
        sq  += psq[((size_t)g * 8 + j) * HIDC + c];
    }
    int cn = starts[g + 1] - starts[g]; if (cn < 1) cn = 1;
    float cnt = (float)cn;
    float m = sum / cnt;
    float a = ld1(alpha, (size_t)aOff + c, *dtf);
    gmean[g * HIDC + c] = m;
    gvar[g * HIDC + c] = fmaxf(sq / cnt - (2.f * a - a * a) * m * m, 0.f);
}

// ---------------- GraphNorm apply ----------------
__global__ void k_nrm(bfu* __restrict__ h, const int* __restrict__ batch,
                      const float* __restrict__ gmean, const float* __restrict__ gvar,
                      const void* __restrict__ gamma, const void* __restrict__ beta,
                      const void* __restrict__ alpha, long pOff,
                      const int* __restrict__ dtf) {
    int tid = blockIdx.x * blockDim.x + threadIdx.x;
    if (tid >= NN * 64) return;
    int bf = *dtf;
    int n = tid >> 6, q = (tid & 63) << 2;
    int g = batch[n]; if ((unsigned)g >= (unsigned)NG) g = 0;
    ushort4 hu = *(ushort4*)(h + (size_t)n * HIDC + q);
    const float4 mv = *(const float4*)(gmean + g * HIDC + q);
    const float4 vv = *(const float4*)(gvar + g * HIDC + q);
    float4 ga = ld4(gamma, (size_t)pOff + q, bf);
    float4 be = ld4(beta, (size_t)pOff + q, bf);
    float4 al = ld4(alpha, (size_t)pOff + q, bf);
    float4 v;
    v.x = ga.x * (bf2f(hu.x) - al.x * mv.x) * rsqrtf(vv.x + EPSN) + be.x;
    v.y = ga.y * (bf2f(hu.y) - al.y * mv.y) * rsqrtf(vv.y + EPSN) + be.y;
    v.z = ga.z * (bf2f(hu.z) - al.z * mv.z) * rsqrtf(vv.z + EPSN) + be.z;
    v.w = ga.w * (bf2f(hu.w) - al.w * mv.w) * rsqrtf(vv.w + EPSN) + be.w;
    ushort4 ov; ov.x = f2bf(v.x); ov.y = f2bf(v.y); ov.z = f2bf(v.z); ov.w = f2bf(v.w);
    *(ushort4*)(h + (size_t)n * HIDC + q) = ov;
}

// ---------------- closed-form final pool ----------------
__global__ void k_pl2(const int* __restrict__ starts,
                      const float* __restrict__ gmean, const float* __restrict__ gvar,
                      const void* __restrict__ gamma, const void* __restrict__ beta,
                      const void* __restrict__ alpha, long pOff,
                      float* __restrict__ g, const int* __restrict__ dtf) {
    int bf = *dtf;
    int gb = blockIdx.x, c = threadIdx.x;
    int cn = starts[gb + 1] - starts[gb];
    if (cn <= 0) { g[gb * HIDC + c] = 0.f; return; }
    float m = gmean[gb * HIDC + c];
    float v = gvar[gb * HIDC + c];
    float ga = ld1(gamma, (size_t)pOff + c, bf);
    float be = ld1(beta, (size_t)pOff + c, bf);
    float al = ld1(alpha, (size_t)pOff + c, bf);
    g[gb * HIDC + c] = ga * (1.f - al) * m * rsqrtf(v + EPSN) + be;
}

// ---------------- head MLP ----------------
__global__ void k_hd(const float* __restrict__ g, const void* __restrict__ bio,
                     const void* __restrict__ W1, const void* __restrict__ b1,
                     const void* __restrict__ W2, const void* __restrict__ b2,
                     void* __restrict__ out, const int* __restrict__ dtf) {
    __shared__ float comb[768];
    __shared__ float red[256];
    __shared__ int nanf;
    int bf = *dtf;
    int gb = blockIdx.x, t = threadIdx.x;
    if (t == 0) nanf = 0;
    comb[t] = g[gb * HIDC + t];
    comb[256 + t] = ld1(bio, t, bf);
    comb[512 + t] = ld1(bio, 256 + t, bf);
    __syncthreads();
    float acc = ld1(b1, t, bf);
    for (int k = 0; k < 768; ++k) acc += comb[k] * ld1(W1, (size_t)k * HIDC + t, bf);
    if (isnan(acc) || isinf(acc)) nanf = 1;
    float hid = fmaxf(acc, 0.f);
    red[t] = hid * ld1(W2, t, bf);
    __syncthreads();
    for (int off = 128; off > 0; off >>= 1) {
        if (t < off) red[t] += red[t + off];
        __syncthreads();
    }
    if (t == 0) {
        float r = red[0] + ld1(b2, 0, bf);
        if (nanf || isnan(r)) r = 999.0f;
        st1(out, gb, r, bf);
    }
}

extern "C" void kernel_launch(void* const* d_in, const int* in_sizes, int n_in,
                              void* d_out, int out_size, void* d_ws, size_t ws_size,
                              hipStream_t stream) {
    const int* x = (const int*)d_in[0];
    const int* ei = (const int*)d_in[1];
    const void* eattr = d_in[2];
    const int* batch = (const int*)d_in[3];
    const void* node_emb_W = d_in[4];
    const void* edge_emb_W = d_in[5];
    const void* edge_emb_b = d_in[6];
    const void* emlp_W1 = d_in[7];
    const void* emlp_b1 = d_in[8];
    const void* emlp_W2 = d_in[9];
    const void* emlp_b2 = d_in[10];
    const void* struct_scale = d_in[11];
    const void* conv_W1 = d_in[12];
    const void* conv_b1 = d_in[13];
    const void* conv_W2 = d_in[14];
    const void* conv_b2 = d_in[15];
    const void* conv_eps = d_in[16];
    const void* ngamma = d_in[17];
    const void* nbeta = d_in[18];
    const void* nalpha = d_in[19];
    const void* mean_bio = d_in[20];
    const void* head_W1 = d_in[21];
    const void* head_b1 = d_in[22];
    const void* head_W2 = d_in[23];
    const void* head_b2 = d_in[24];
    (void)in_sizes; (void)n_in; (void)out_size; (void)ws_size;

    // Layout — TOTAL ~214.1 MB < 258 MB proven-safe:
    //   h 51.2M | agg 51.2M | e8 102.4M (fp8, once) | wt 1.05M | csr 4.01M |
    //   ps 4.19M | small
    const size_t H_B = (size_t)NN * HIDC * 2;
    const size_t E8_B = (size_t)NE * HIDC;
    char* p = (char*)d_ws;
    bfu* hbuf = (bfu*)p; p += H_B;
    bfu* aggb = (bfu*)p; p += H_B;
    unsigned char* e8 = (unsigned char*)p; p += E8_B;
    bfu* wt = (bfu*)p; p += 8 * 65536 * 2;
    int* rowp = (int*)p;
    int* cursor = rowp + 100352;
    int* part = cursor + 100352;
    int* splits = part + 1024;
    int* cnts = splits + 8;
    int* csrc = cnts + 8;
    int* ceid = csrc + NE;
    p = (char*)(ceid + NE);
    float* psum = (float*)p; p += (size_t)NG * 8 * HIDC * 4;
    float* psq = (float*)p; p += (size_t)NG * 8 * HIDC * 4;
    char* small = p;
    int* starts = (int*)small;
    int* dtf = (int*)(small + 2048);
    float* weff = (float*)(small + 4096);       // 4x256 f32 = 4 KB
    float* beff = weff + 4 * HIDC;              // 256 f32 = 1 KB (ends < 16384)
    float* gmean = (float*)(small + 16384);
    float* gvar = gmean + NG * HIDC;
    float* gpool = gvar + NG * HIDC;
    (void)splits; (void)cnts;

    k_dt2<<<1, 64, 0, stream>>>((const unsigned int*)ngamma, dtf);
    k_st2<<<1, 512, 0, stream>>>(batch, starts);
    k_emb<<<(NN * 64 + 255) / 256, 256, 0, stream>>>(x, node_emb_W, hbuf, dtf);
    k_wef<<<5, 256, 0, stream>>>(edge_emb_W, edge_emb_b, emlp_W1, emlp_b1,
                                 weff, beff, dtf);

    k_wtr<<<256, 256, 0, stream>>>(emlp_W2, 0, wt + 65536, dtf);
    for (int l = 0; l < 3; ++l) {
        k_wtr<<<256, 256, 0, stream>>>(conv_W1, (long)l * HIDC * HIDC, wt + (2 + l) * 65536, dtf);
        k_wtr<<<256, 256, 0, stream>>>(conv_W2, (long)l * HIDC * HIDC, wt + (5 + l) * 65536, dtf);
    }

    const int NBN = (NN + 255) / 256;
    k_zi<<<NBN, 256, 0, stream>>>(cursor, NN);
    k_cnt<<<(NE + 255) / 256, 256, 0, stream>>>(ei, cursor);
    k_sc1<<<NBN, 256, 0, stream>>>(cursor, rowp, part);
    k_sc2<<<1, 64, 0, stream>>>(part, NBN);
    k_sc3<<<NBN, 256, 0, stream>>>(rowp, part);
    k_cpi<<<NBN, 256, 0, stream>>>(rowp, cursor, NN);
    k_fil<<<(NE + 255) / 256, 256, 0, stream>>>(ei, cursor, csrc, ceid);

    // e computed ONCE: e8 = fp8[(relu(attr@weff+beff) @ W2 + b2) * scale]
    dim3 gE((NE + 63) / 64), gN((NN + 63) / 64);
    k_me<<<gE, 512, 0, stream>>>(eattr, weff, beff, wt + 65536, emlp_b2,
                                 struct_scale, e8, dtf, ceid);

    dim3 gS1(NG, 8);
    const int gatBlocks = (NN * 64 + 255) / 256;

    for (int l = 0; l < 3; ++l) {
        k_gat3<<<gatBlocks, 256, 0, stream>>>(hbuf, e8, rowp, csrc, aggb);
        // fused conv: h = relu(((1+eps)h+agg)@W1+b1)@W2+b2, in-place on h
        k_cnv<<<gN, 256, 0, stream>>>(
            hbuf, aggb, conv_eps, l,
            wt + (2 + l) * 65536, conv_b1, (long)l * HIDC,
            wt + (5 + l) * 65536, conv_b2, (long)l * HIDC, dtf);
        k_s1<<<gS1, 256, 0, stream>>>(hbuf, starts, psum, psq);
        k_s2<<<NG, 256, 0, stream>>>(starts, psum, psq, nalpha, (long)l * HIDC,
                                     gmean, gvar, dtf);
        if (l < 2) {
            k_nrm<<<(NN * 64 + 255) / 256, 256, 0, stream>>>(
                hbuf, batch, gmean, gvar, ngamma, nbeta, nalpha, (long)l * HIDC, dtf);
        }
    }

    k_pl2<<<NG, 256, 0, stream>>>(starts, gmean, gvar, ngamma, nbeta, nalpha,
                                  (long)2 * HIDC, gpool, dtf);
    k_hd<<<NG, 256, 0, stream>>>(gpool, mean_bio, head_W1, head_b1,
                                 head_W2, head_b2, d_out, dtf);
}

// Round 8
// 977.126 us; speedup vs baseline: 1.0440x; 1.0440x over previous
//
#include <hip/hip_runtime.h>
#include <cstddef>

#define NN 100000
#define NE 400000
#define NG 256
#define HIDC 256
#define EPSN 1e-5f

typedef unsigned short bfu;  // bf16 bits
using short8 = __attribute__((ext_vector_type(8))) short;
using f32x4  = __attribute__((ext_vector_type(4))) float;
using f32x2  = __attribute__((ext_vector_type(2))) float;

#if defined(__has_builtin)
#if __has_builtin(__builtin_amdgcn_cvt_pk_fp8_f32) && __has_builtin(__builtin_amdgcn_cvt_pk_f32_fp8)
#define HWFP8 1
#endif
#endif

__device__ __forceinline__ float bf2f(bfu b) {
    union { unsigned int u; float f; } v; v.u = ((unsigned int)b) << 16; return v.f;
}
__device__ __forceinline__ bfu f2bf(float f) {
    union { float f; unsigned int u; } v; v.f = f;
    unsigned int r = v.u + 0x7FFFu + ((v.u >> 16) & 1u);
    return (bfu)(r >> 16);
}
// ---- fp8 e4m3 software fallback ----
__device__ __forceinline__ float e4m3f_sw(unsigned char b) {
    unsigned s = ((unsigned)(b & 0x80u)) << 24;
    unsigned E = (b >> 3) & 15u, M = b & 7u;
    union { unsigned x; float f; } o;
    if (E == 0) { o.f = (float)M * 0.001953125f; o.x |= s; }
    else o.x = s | ((E + 120u) << 23) | (M << 20);
    return o.f;
}
__device__ __forceinline__ unsigned char f2e4m3_sw(float f) {
    union { float f; unsigned u; } v; v.f = f;
    unsigned s = (v.u >> 24) & 0x80u;
    float a = fabsf(f);
    if (!(a < 448.f)) return (unsigned char)(s | 0x7Eu);
    if (a < 0.0009765625f) return (unsigned char)s;
    if (a < 0.015625f) {
        int m = (int)(a * 512.f + 0.5f);
        if (m >= 8) return (unsigned char)(s | 0x08u);
        return (unsigned char)(s | (unsigned)m);
    }
    unsigned u = v.u;
    unsigned r = u + 0x7FFFFu + ((u >> 20) & 1u);
    int E = (int)((r >> 23) & 255u) - 127 + 7;
    unsigned M = (r >> 20) & 7u;
    if (E >= 16) return (unsigned char)(s | 0x7Eu);
    if (E <= 0) {
        int m = (int)(a * 512.f + 0.5f); if (m > 7) m = 7;
        return (unsigned char)(s | (unsigned)m);
    }
    return (unsigned char)(s | ((unsigned)E << 3) | M);
}
// ---- 4-wide fp8 pack/unpack (HW when available) ----
__device__ __forceinline__ unsigned int fp8enc4(float a, float b, float c, float d) {
#ifdef HWFP8
    int lo = __builtin_amdgcn_cvt_pk_fp8_f32(a, b, 0, false);
    int hi = __builtin_amdgcn_cvt_pk_fp8_f32(c, d, 0, false);
    return (unsigned int)((lo & 0xFFFF) | (hi << 16));
#else
    return (unsigned)f2e4m3_sw(a) | ((unsigned)f2e4m3_sw(b) << 8) |
           ((unsigned)f2e4m3_sw(c) << 16) | ((unsigned)f2e4m3_sw(d) << 24);
#endif
}
__device__ __forceinline__ float4 fp8dec4(unsigned int u) {
#ifdef HWFP8
    f32x2 lo = __builtin_amdgcn_cvt_pk_f32_fp8((int)u, false);
    f32x2 hi = __builtin_amdgcn_cvt_pk_f32_fp8((int)u, true);
    return make_float4(lo[0], lo[1], hi[0], hi[1]);
#else
    return make_float4(e4m3f_sw(u & 255u), e4m3f_sw((u >> 8) & 255u),
                       e4m3f_sw((u >> 16) & 255u), e4m3f_sw((u >> 24) & 255u));
#endif
}
__device__ __forceinline__ float4 ld4(const void* p, size_t i, int bf) {
    if (bf) {
        ushort4 u = *(const ushort4*)((const bfu*)p + i);
        return make_float4(bf2f(u.x), bf2f(u.y), bf2f(u.z), bf2f(u.w));
    }
    return *(const float4*)((const float*)p + i);
}
__device__ __forceinline__ float ld1(const void* p, size_t i, int bf) {
    return bf ? bf2f(((const bfu*)p)[i]) : ((const float*)p)[i];
}
__device__ __forceinline__ void st1(void* p, size_t i, float v, int bf) {
    if (bf) ((bfu*)p)[i] = f2bf(v); else ((float*)p)[i] = v;
}

// ---------------- dtype detect ----------------
__global__ void k_dt2(const unsigned int* __restrict__ g, int* __restrict__ flag) {
    if (threadIdx.x == 0)
        flag[0] = (g[0] == 0x3F800000u) ? 0 : 1;
}

// ---------------- graph starts (batch sorted) ----------------
__global__ void k_st2(const int* __restrict__ batch, int* __restrict__ starts) {
    int g = threadIdx.x;
    if (g > NG) return;
    if (g == NG) { starts[NG] = NN; return; }
    int lo = 0, hi = NN;
    while (lo < hi) { int mid = (lo + hi) >> 1; if (batch[mid] < g) lo = mid + 1; else hi = mid; }
    starts[g] = lo;
}

__global__ void k_zi(int* __restrict__ p, int n) {
    int i = blockIdx.x * blockDim.x + threadIdx.x;
    if (i < n) p[i] = 0;
}

// ---------------- CSR build ----------------
__global__ void k_cnt(const int* __restrict__ ei, int* __restrict__ deg) {
    int e = blockIdx.x * blockDim.x + threadIdx.x;
    if (e >= NE) return;
    int d = ei[NE + e];
    if ((unsigned)d < (unsigned)NN) atomicAdd(&deg[d], 1);
}
__global__ void k_sc1(const int* __restrict__ deg, int* __restrict__ rowp,
                      int* __restrict__ part) {
    __shared__ int sh[256];
    int b = blockIdx.x, t = threadIdx.x;
    int i = b * 256 + t;
    int v = (i < NN) ? deg[i] : 0;
    sh[t] = v; __syncthreads();
    for (int off = 1; off < 256; off <<= 1) {
        int add = (t >= off) ? sh[t - off] : 0;
        __syncthreads();
        sh[t] += add; __syncthreads();
    }
    if (i < NN) rowp[i] = sh[t] - v;
    if (t == 255) part[b] = sh[255];
}
__global__ void k_sc2(int* __restrict__ part, int nb) {
    if (threadIdx.x != 0) return;
    int run = 0;
    for (int b = 0; b < nb; ++b) { int t = part[b]; part[b] = run; run += t; }
}
__global__ void k_sc3(int* __restrict__ rowp, const int* __restrict__ part) {
    int i = blockIdx.x * blockDim.x + threadIdx.x;
    if (i < NN) rowp[i] += part[blockIdx.x];
    if (i == 0) rowp[NN] = NE;
}
__global__ void k_cpi(const int* __restrict__ a, int* __restrict__ b, int n) {
    int i = blockIdx.x * blockDim.x + threadIdx.x;
    if (i < n) b[i] = a[i];
}
__global__ void k_fil(const int* __restrict__ ei, int* __restrict__ cursor,
                      int* __restrict__ csrc, int* __restrict__ ceid) {
    int e = blockIdx.x * blockDim.x + threadIdx.x;
    if (e >= NE) return;
    int s = ei[e], d = ei[NE + e];
    if ((unsigned)d >= (unsigned)NN) return;
    int pos = atomicAdd(&cursor[d], 1);
    csrc[pos] = ((unsigned)s < (unsigned)NN) ? s : 0;
    ceid[pos] = e;
}

// ---------------- Weff = Wemb @ W1 (4x256) f32, beff = bemb @ W1 + b1 f32 ------
__global__ void k_wef(const void* __restrict__ Wemb, const void* __restrict__ bemb,
                      const void* __restrict__ W1, const void* __restrict__ b1,
                      float* __restrict__ weff, float* __restrict__ beff,
                      const int* __restrict__ dtf) {
    int bf = *dtf;
    int j = blockIdx.x;
    int n = threadIdx.x;
    float acc = 0.f;
    if (j < 4) {
        for (int k = 0; k < HIDC; ++k)
            acc += ld1(Wemb, (size_t)j * HIDC + k, bf) * ld1(W1, (size_t)k * HIDC + n, bf);
        weff[j * HIDC + n] = acc;
    } else {
        for (int k = 0; k < HIDC; ++k)
            acc += ld1(bemb, k, bf) * ld1(W1, (size_t)k * HIDC + n, bf);
        beff[n] = acc + ld1(b1, n, bf);
    }
}

// ---------------- CSR gather v2: 32 thr/node x 8 ch, 2-edge unroll ------------
__device__ __forceinline__ void acc8(float* a, uint4 hv, uint2 ev) {
    float4 e0 = fp8dec4(ev.x);
    float4 e1 = fp8dec4(ev.y);
    a[0] += fmaxf(bf2f((bfu)(hv.x & 0xFFFFu)) + e0.x, 0.f);
    a[1] += fmaxf(bf2f((bfu)(hv.x >> 16))    + e0.y, 0.f);
    a[2] += fmaxf(bf2f((bfu)(hv.y & 0xFFFFu)) + e0.z, 0.f);
    a[3] += fmaxf(bf2f((bfu)(hv.y >> 16))    + e0.w, 0.f);
    a[4] += fmaxf(bf2f((bfu)(hv.z & 0xFFFFu)) + e1.x, 0.f);
    a[5] += fmaxf(bf2f((bfu)(hv.z >> 16))    + e1.y, 0.f);
    a[6] += fmaxf(bf2f((bfu)(hv.w & 0xFFFFu)) + e1.z, 0.f);
    a[7] += fmaxf(bf2f((bfu)(hv.w >> 16))    + e1.w, 0.f);
}
__global__ void k_gat4(const bfu* __restrict__ h, const unsigned char* __restrict__ e8,
                       const int* __restrict__ rowp, const int* __restrict__ csrc,
                       bfu* __restrict__ agg) {
    int tid = blockIdx.x * blockDim.x + threadIdx.x;
    if (tid >= NN * 32) return;
    int n = tid >> 5, q = (tid & 31) << 3;   // 8 channels per thread
    int s0 = rowp[n], s1 = rowp[n + 1];
    float a[8] = {};
    int i = s0;
    for (; i + 2 <= s1; i += 2) {
        int src0 = csrc[i], src1 = csrc[i + 1];
        uint4 h0 = *(const uint4*)(h + (size_t)src0 * HIDC + q);
        uint4 h1 = *(const uint4*)(h + (size_t)src1 * HIDC + q);
        uint2 e0 = *(const uint2*)(e8 + (size_t)i * HIDC + q);
        uint2 e1 = *(const uint2*)(e8 + (size_t)(i + 1) * HIDC + q);
        acc8(a, h0, e0);
        acc8(a, h1, e1);
    }
    if (i < s1) {
        int src0 = csrc[i];
        uint4 h0 = *(const uint4*)(h + (size_t)src0 * HIDC + q);
        uint2 e0 = *(const uint2*)(e8 + (size_t)i * HIDC + q);
        acc8(a, h0, e0);
    }
    ushort4 o0, o1;
    o0.x = f2bf(a[0]); o0.y = f2bf(a[1]); o0.z = f2bf(a[2]); o0.w = f2bf(a[3]);
    o1.x = f2bf(a[4]); o1.y = f2bf(a[5]); o1.z = f2bf(a[6]); o1.w = f2bf(a[7]);
    *(ushort4*)(agg + (size_t)n * HIDC + q) = o0;
    *(ushort4*)(agg + (size_t)n * HIDC + q + 4) = o1;
}

// ---------------- weight transpose to MFMA-fragment-swizzled bf16 ----------------
__global__ void k_wtr(const void* __restrict__ W, long wOff, bfu* __restrict__ Wt,
                      const int* __restrict__ dtf) {
    int o = blockIdx.x * blockDim.x + threadIdx.x;
    if (o >= HIDC * HIDC) return;
    int blk = o >> 9, pos = o & 511;
    int w = blk >> 5, rem = blk & 31;
    int t = rem >> 3, kb = rem & 7;
    int pr = pos >> 3, j = pos & 7;
    int lr = pr >> 2, lq = pr & 3;
    int n = w * 64 + t * 16 + lr;
    int k = kb * 32 + lq * 8 + j;
    Wt[o] = f2bf(ld1(W, (size_t)wOff + (size_t)k * HIDC + n, *dtf));
}

// ---------------- node embedding gather ----------------
__global__ void k_emb(const int* __restrict__ x, const void* __restrict__ W,
                      bfu* __restrict__ h, const int* __restrict__ dtf) {
    int tid = blockIdx.x * blockDim.x + threadIdx.x;
    if (tid >= NN * 64) return;
    int bf = *dtf;
    int n = tid >> 6, q = (tid & 63) << 2;
    int xv = x[n]; if ((unsigned)xv >= 8u) xv = 0;
    float4 v = ld4(W, (size_t)xv * HIDC + q, bf);
    ushort4 o; o.x = f2bf(v.x); o.y = f2bf(v.y); o.z = f2bf(v.z); o.w = f2bf(v.w);
    *(ushort4*)(h + (size_t)n * HIDC + q) = o;
}

// ---------------- edge MLP: e8 = fp8[(relu(attr@weff+beff) @ W2 + b2) * scale] --
// v7 = v5 exactly (measured best: 156.8 us, WRITE 200 MB, FETCH 70 MB).
// v6's "perfect" dense stores measured WORSE (262/102) -> store-amplification
// here is concurrency/timing dependent, not per-instruction line coverage;
// keep the empirically best indexing (tid*32 pair).
__global__ __launch_bounds__(512, 8)
void k_me(const void* __restrict__ attrs,
          const float* __restrict__ weff, const float* __restrict__ beff,
          const bfu* __restrict__ Wt, const void* __restrict__ bias,
          const void* __restrict__ scalep,
          unsigned char* __restrict__ C,
          const int* __restrict__ dtf, const int* __restrict__ eidx) {
    __shared__ bfu As[4][64 * 32];   // 16 KB: A-tiles, then fp8 output staging
    __shared__ float wsh[1280];      // weff 4x256 | beff 256
    __shared__ float sf[64];
    const int bf = *dtf;
    const int tid = threadIdx.x;
    const int wave = tid >> 6, lane = tid & 63;
    const int lr = lane & 15, lq = lane >> 4;
    const int wr = wave >> 2, wc = wave & 3;   // row half / col quarter
    const int m0 = blockIdx.x * 64;
    const int row = tid >> 3;                  // 0..63
    const int a4 = (tid & 7) << 2;             // 0..28, 4 cols per thread

    for (int v = tid; v < 1280; v += 512)
        wsh[v] = (v < 1024) ? weff[v] : beff[v - 1024];

    float aa[4];
    {
        long er = (long)eidx[m0 + row];
        aa[0] = ld1(attrs, (size_t)er * 4 + 0, bf);
        aa[1] = ld1(attrs, (size_t)er * 4 + 1, bf);
        aa[2] = ld1(attrs, (size_t)er * 4 + 2, bf);
        aa[3] = ld1(attrs, (size_t)er * 4 + 3, bf);
    }
    if ((tid & 7) == 0)
        sf[row] = (aa[1] > 0.f) ? ld1(scalep, 0, bf) : 1.0f;
    __syncthreads();   // wsh + sf ready

    f32x4 acc[2][4] = {};
    const bfu* wb = Wt + ((size_t)wc * 32) * 512 + (size_t)(lr * 4 + lq) * 8;

    for (int h = 0; h < 2; ++h) {
        if (h) __syncthreads();   // prior MFMA reads of As complete
#pragma unroll
        for (int q = 0; q < 4; ++q) {
            const int c = h * 128 + q * 32 + a4;
            float4 bb = *(const float4*)(wsh + 1024 + c);
            float v0 = bb.x, v1 = bb.y, v2 = bb.z, v3 = bb.w;
#pragma unroll
            for (int j = 0; j < 4; ++j) {
                float4 w0 = *(const float4*)(wsh + j * 256 + c);
                v0 += aa[j] * w0.x; v1 += aa[j] * w0.y;
                v2 += aa[j] * w0.z; v3 += aa[j] * w0.w;
            }
            ushort4 o;
            o.x = f2bf(fmaxf(v0, 0.f)); o.y = f2bf(fmaxf(v1, 0.f));
            o.z = f2bf(fmaxf(v2, 0.f)); o.w = f2bf(fmaxf(v3, 0.f));
            *(ushort4*)(&As[q][row * 32 + a4]) = o;
        }
        __syncthreads();
#pragma unroll
        for (int q = 0; q < 4; ++q) {
            const int kb = h * 4 + q;
            short8 fa0 = *(const short8*)(&As[q][(wr * 32 + lr) * 32 + lq * 8]);
            short8 fa1 = *(const short8*)(&As[q][(wr * 32 + 16 + lr) * 32 + lq * 8]);
#pragma unroll
            for (int t = 0; t < 4; ++t) {
                short8 fb = *(const short8*)(wb + (size_t)(t * 8 + kb) * 512);
                acc[0][t] = __builtin_amdgcn_mfma_f32_16x16x32_bf16(fa0, fb, acc[0][t], 0, 0, 0);
                acc[1][t] = __builtin_amdgcn_mfma_f32_16x16x32_bf16(fa1, fb, acc[1][t], 0, 0, 0);
            }
        }
    }
    __syncthreads();   // all MFMA reads of As done; reuse As as output staging

    // ---- epilogue: fp8 tile -> LDS (byte writes), then coalesced global ----
    unsigned char* tile = (unsigned char*)&As[0][0];   // [64 rows][256 cols]
    float bv[4];
#pragma unroll
    for (int t = 0; t < 4; ++t)
        bv[t] = ld1(bias, (size_t)(wc * 64 + t * 16 + lr), bf);
#pragma unroll
    for (int r = 0; r < 2; ++r) {
#pragma unroll
        for (int i = 0; i < 4; ++i) {
            int rr = wr * 32 + r * 16 + lq * 4 + i;
            float rs = sf[rr];
            float ov0 = (acc[r][0][i] + bv[0]) * rs;
            float ov1 = (acc[r][1][i] + bv[1]) * rs;
            float ov2 = (acc[r][2][i] + bv[2]) * rs;
            float ov3 = (acc[r][3][i] + bv[3]) * rs;
            unsigned int pk = fp8enc4(ov0, ov1, ov2, ov3);
            int cb = rr * 256 + wc * 64 + lr;
            tile[cb]      = (unsigned char)(pk & 255u);
            tile[cb + 16] = (unsigned char)((pk >> 8) & 255u);
            tile[cb + 32] = (unsigned char)((pk >> 16) & 255u);
            tile[cb + 48] = (unsigned char)(pk >> 24);
        }
    }
    __syncthreads();
    // v5 store indexing (measured best)
    {
        const uint4* lsrc = (const uint4*)(tile + tid * 32);
        uint4 w0 = lsrc[0];
        uint4 w1 = lsrc[1];
        uint4* gdst = (uint4*)(C + (size_t)m0 * HIDC + (size_t)tid * 32);
        gdst[0] = w0;
        gdst[1] = w1;
    }
}

// ---------------- fused GINE conv: h = (relu(((1+eps)h+agg)@W1+b1))@W2+b2 -------
__global__ __launch_bounds__(256)
void k_cnv(bfu* __restrict__ h, const bfu* __restrict__ agg,
           const void* __restrict__ eps, int epsIdx,
           const bfu* __restrict__ Wt1, const void* __restrict__ bias1, long b1Off,
           const bfu* __restrict__ Wt2, const void* __restrict__ bias2, long b2Off,
           const int* __restrict__ dtf) {
    __shared__ bfu Ts[8][64 * 32];   // 32 KB: Z tiles (phase 1), then T tiles (phase 2)
    const int bf = *dtf;
    const int tid = threadIdx.x;
    const int wave = tid >> 6, lane = tid & 63;
    const int lr = lane & 15, lq = lane >> 4;
    const int m0 = blockIdx.x * 64;
    const float epsv = 1.0f + ld1(eps, epsIdx, bf);
    const int row = tid >> 2;
    const int ak = (tid & 3) << 3;
    const int gmA = m0 + row;
    const bfu* wb1 = Wt1 + ((size_t)wave * 32) * 512 + (size_t)(lr * 4 + lq) * 8;
    const bfu* wb2 = Wt2 + ((size_t)wave * 32) * 512 + (size_t)(lr * 4 + lq) * 8;

    // ---- phase 0: Z = (1+eps)h + agg -> LDS ----
#pragma unroll
    for (int k0 = 0; k0 < 256; k0 += 32) {
        float hv[8] = {}, gv[8] = {};
        if (gmA < NN) {
            ushort4 h0 = *(const ushort4*)(h + (size_t)gmA * HIDC + k0 + ak);
            ushort4 h1 = *(const ushort4*)(h + (size_t)gmA * HIDC + k0 + ak + 4);
            hv[0]=bf2f(h0.x); hv[1]=bf2f(h0.y); hv[2]=bf2f(h0.z); hv[3]=bf2f(h0.w);
            hv[4]=bf2f(h1.x); hv[5]=bf2f(h1.y); hv[6]=bf2f(h1.z); hv[7]=bf2f(h1.w);
            ushort4 g0 = *(const ushort4*)(agg + (size_t)gmA * HIDC + k0 + ak);
            ushort4 g1 = *(const ushort4*)(agg + (size_t)gmA * HIDC + k0 + ak + 4);
            gv[0]=bf2f(g0.x); gv[1]=bf2f(g0.y); gv[2]=bf2f(g0.z); gv[3]=bf2f(g0.w);
            gv[4]=bf2f(g1.x); gv[5]=bf2f(g1.y); gv[6]=bf2f(g1.z); gv[7]=bf2f(g1.w);
        }
        ushort4 o0, o1;
        o0.x = f2bf(epsv * hv[0] + gv[0]); o0.y = f2bf(epsv * hv[1] + gv[1]);
        o0.z = f2bf(epsv * hv[2] + gv[2]); o0.w = f2bf(epsv * hv[3] + gv[3]);
        o1.x = f2bf(epsv * hv[4] + gv[4]); o1.y = f2bf(epsv * hv[5] + gv[5]);
        o1.z = f2bf(epsv * hv[6] + gv[6]); o1.w = f2bf(epsv * hv[7] + gv[7]);
        *(ushort4*)(&Ts[k0 >> 5][row * 32 + ak]) = o0;
        *(ushort4*)(&Ts[k0 >> 5][row * 32 + ak + 4]) = o1;
    }
    __syncthreads();

    // ---- phase 1: T = Z @ W1 ----
    f32x4 acc[4][4] = {};
#pragma unroll
    for (int kb = 0; kb < 8; ++kb) {
        short8 fa[4], fbv[4];
#pragma unroll
        for (int r = 0; r < 4; ++r)
            fa[r] = *(const short8*)(&Ts[kb][(r * 16 + lr) * 32 + lq * 8]);
#pragma unroll
        for (int t = 0; t < 4; ++t)
            fbv[t] = *(const short8*)(wb1 + (size_t)(t * 8 + kb) * 512);
#pragma unroll
        for (int r = 0; r < 4; ++r)
#pragma unroll
            for (int t = 0; t < 4; ++t)
                acc[r][t] = __builtin_amdgcn_mfma_f32_16x16x32_bf16(
                    fa[r], fbv[t], acc[r][t], 0, 0, 0);
    }
    __syncthreads();

    // ---- T = relu(acc + b1) -> Ts (overwrite), reset acc ----
    {
        float bv[4];
#pragma unroll
        for (int t = 0; t < 4; ++t)
            bv[t] = ld1(bias1, (size_t)b1Off + wave * 64 + t * 16 + lr, bf);
        const f32x4 z4 = {0.f, 0.f, 0.f, 0.f};
#pragma unroll
        for (int r = 0; r < 4; ++r) {
#pragma unroll
            for (int i = 0; i < 4; ++i) {
                int rowo = r * 16 + lq * 4 + i;
#pragma unroll
                for (int t = 0; t < 4; ++t) {
                    int kk = wave * 64 + t * 16 + lr;
                    Ts[kk >> 5][rowo * 32 + (kk & 31)] =
                        f2bf(fmaxf(acc[r][t][i] + bv[t], 0.f));
                }
            }
        }
#pragma unroll
        for (int r = 0; r < 4; ++r)
#pragma unroll
            for (int t = 0; t < 4; ++t)
                acc[r][t] = z4;
    }
    __syncthreads();

    // ---- phase 2: h = T @ W2 + b2 ----
#pragma unroll
    for (int kb = 0; kb < 8; ++kb) {
        short8 fa[4], fbv[4];
#pragma unroll
        for (int r = 0; r < 4; ++r)
            fa[r] = *(const short8*)(&Ts[kb][(r * 16 + lr) * 32 + lq * 8]);
#pragma unroll
        for (int t = 0; t < 4; ++t)
            fbv[t] = *(const short8*)(wb2 + (size_t)(t * 8 + kb) * 512);
#pragma unroll
        for (int r = 0; r < 4; ++r)
#pragma unroll
            for (int t = 0; t < 4; ++t)
                acc[r][t] = __builtin_amdgcn_mfma_f32_16x16x32_bf16(
                    fa[r], fbv[t], acc[r][t], 0, 0, 0);
    }
    float bv[4];
#pragma unroll
    for (int t = 0; t < 4; ++t)
        bv[t] = ld1(bias2, (size_t)b2Off + wave * 64 + t * 16 + lr, bf);
#pragma unroll
    for (int r = 0; r < 4; ++r) {
#pragma unroll
        for (int i = 0; i < 4; ++i) {
            int gm = m0 + r * 16 + lq * 4 + i;
            if (gm >= NN) continue;
            size_t cbase = (size_t)gm * HIDC + wave * 64 + lr;
#pragma unroll
            for (int t = 0; t < 4; ++t)
                h[cbase + t * 16] = f2bf(acc[r][t][i] + bv[t]);
        }
    }
}

// ---------------- GraphNorm stats: stage 1 (partials) + stage 2 (reduce) -------
__global__ void k_s1(const bfu* __restrict__ h, const int* __restrict__ starts,
                     float* __restrict__ psum, float* __restrict__ psq) {
    int g = blockIdx.x, c8 = blockIdx.y, c = threadIdx.x;
    int s = starts[g], t = starts[g + 1];
    int len = t - s;
    int b = s + (int)(((long)len * c8) >> 3);
    int e = s + (int)(((long)len * (c8 + 1)) >> 3);
    float sum = 0.f, sq = 0.f;
    for (int n = b; n < e; ++n) {
        float v = bf2f(h[(size_t)n * HIDC + c]);
        sum += v; sq += v * v;
    }
    psum[((size_t)g * 8 + c8) * HIDC + c] = sum;
    psq[((size_t)g * 8 + c8) * HIDC + c] = sq;
}
__global__ void k_s2(const int* __restrict__ starts,
                     const float* __restrict__ psum, const float* __restrict__ psq,
                     const void* __restrict__ alpha, long aOff,
                     float* __restrict__ gmean, float* __restrict__ gvar,
                     const int* __restrict__ dtf) {
    int g = blockIdx.x, c = threadIdx.x;
    float sum = 0.f, sq = 0.f;
#pragma unroll
    for (int j = 0; j < 8; ++j) {
        sum += psum[((size_t)g * 8 + j) * HIDC + c];
        sq  += psq[((size_t)g * 8 + j) * HIDC + c];
    }
    int cn = starts[g + 1] - starts[g]; if (cn < 1) cn = 1;
    float cnt = (float)cn;
    float m = sum / cnt;
    float a = ld1(alpha, (size_t)aOff + c, *dtf);
    gmean[g * HIDC + c] = m;
    gvar[g * HIDC + c] = fmaxf(sq / cnt - (2.f * a - a * a) * m * m, 0.f);
}

// ---------------- GraphNorm apply ----------------
__global__ void k_nrm(bfu* __restrict__ h, const int* __restrict__ batch,
                      const float* __restrict__ gmean, const float* __restrict__ gvar,
                      const void* __restrict__ gamma, const void* __restrict__ beta,
                      const void* __restrict__ alpha, long pOff,
                      const int* __restrict__ dtf) {
    int tid = blockIdx.x * blockDim.x + threadIdx.x;
    if (tid >= NN * 64) return;
    int bf = *dtf;
    int n = tid >> 6, q = (tid & 63) << 2;
    int g = batch[n]; if ((unsigned)g >= (unsigned)NG) g = 0;
    ushort4 hu = *(ushort4*)(h + (size_t)n * HIDC + q);
    const float4 mv = *(const float4*)(gmean + g * HIDC + q);
    const float4 vv = *(const float4*)(gvar + g * HIDC + q);
    float4 ga = ld4(gamma, (size_t)pOff + q, bf);
    float4 be = ld4(beta, (size_t)pOff + q, bf);
    float4 al = ld4(alpha, (size_t)pOff + q, bf);
    float4 v;
    v.x = ga.x * (bf2f(hu.x) - al.x * mv.x) * rsqrtf(vv.x + EPSN) + be.x;
    v.y = ga.y * (bf2f(hu.y) - al.y * mv.y) * rsqrtf(vv.y + EPSN) + be.y;
    v.z = ga.z * (bf2f(hu.z) - al.z * mv.z) * rsqrtf(vv.z + EPSN) + be.z;
    v.w = ga.w * (bf2f(hu.w) - al.w * mv.w) * rsqrtf(vv.w + EPSN) + be.w;
    ushort4 ov; ov.x = f2bf(v.x); ov.y = f2bf(v.y); ov.z = f2bf(v.z); ov.w = f2bf(v.w);
    *(ushort4*)(h + (size_t)n * HIDC + q) = ov;
}

// ---------------- closed-form final pool ----------------
__global__ void k_pl2(const int* __restrict__ starts,
                      const float* __restrict__ gmean, const float* __restrict__ gvar,
                      const void* __restrict__ gamma, const void* __restrict__ beta,
                      const void* __restrict__ alpha, long pOff,
                      float* __restrict__ g, const int* __restrict__ dtf) {
    int bf = *dtf;
    int gb = blockIdx.x, c = threadIdx.x;
    int cn = starts[gb + 1] - starts[gb];
    if (cn <= 0) { g[gb * HIDC + c] = 0.f; return; }
    float m = gmean[gb * HIDC + c];
    float v = gvar[gb * HIDC + c];
    float ga = ld1(gamma, (size_t)pOff + c, bf);
    float be = ld1(beta, (size_t)pOff + c, bf);
    float al = ld1(alpha, (size_t)pOff + c, bf);
    g[gb * HIDC + c] = ga * (1.f - al) * m * rsqrtf(v + EPSN) + be;
}

// ---------------- head MLP ----------------
__global__ void k_hd(const float* __restrict__ g, const void* __restrict__ bio,
                     const void* __restrict__ W1, const void* __restrict__ b1,
                     const void* __restrict__ W2, const void* __restrict__ b2,
                     void* __restrict__ out, const int* __restrict__ dtf) {
    __shared__ float comb[768];
    __shared__ float red[256];
    __shared__ int nanf;
    int bf = *dtf;
    int gb = blockIdx.x, t = threadIdx.x;
    if (t == 0) nanf = 0;
    comb[t] = g[gb * HIDC + t];
    comb[256 + t] = ld1(bio, t, bf);
    comb[512 + t] = ld1(bio, 256 + t, bf);
    __syncthreads();
    float acc = ld1(b1, t, bf);
    for (int k = 0; k < 768; ++k) acc += comb[k] * ld1(W1, (size_t)k * HIDC + t, bf);
    if (isnan(acc) || isinf(acc)) nanf = 1;
    float hid = fmaxf(acc, 0.f);
    red[t] = hid * ld1(W2, t, bf);
    __syncthreads();
    for (int off = 128; off > 0; off >>= 1) {
        if (t < off) red[t] += red[t + off];
        __syncthreads();
    }
    if (t == 0) {
        float r = red[0] + ld1(b2, 0, bf);
        if (nanf || isnan(r)) r = 999.0f;
        st1(out, gb, r, bf);
    }
}

extern "C" void kernel_launch(void* const* d_in, const int* in_sizes, int n_in,
                              void* d_out, int out_size, void* d_ws, size_t ws_size,
                              hipStream_t stream) {
    const int* x = (const int*)d_in[0];
    const int* ei = (const int*)d_in[1];
    const void* eattr = d_in[2];
    const int* batch = (const int*)d_in[3];
    const void* node_emb_W = d_in[4];
    const void* edge_emb_W = d_in[5];
    const void* edge_emb_b = d_in[6];
    const void* emlp_W1 = d_in[7];
    const void* emlp_b1 = d_in[8];
    const void* emlp_W2 = d_in[9];
    const void* emlp_b2 = d_in[10];
    const void* struct_scale = d_in[11];
    const void* conv_W1 = d_in[12];
    const void* conv_b1 = d_in[13];
    const void* conv_W2 = d_in[14];
    const void* conv_b2 = d_in[15];
    const void* conv_eps = d_in[16];
    const void* ngamma = d_in[17];
    const void* nbeta = d_in[18];
    const void* nalpha = d_in[19];
    const void* mean_bio = d_in[20];
    const void* head_W1 = d_in[21];
    const void* head_b1 = d_in[22];
    const void* head_W2 = d_in[23];
    const void* head_b2 = d_in[24];
    (void)in_sizes; (void)n_in; (void)out_size; (void)ws_size;

    // Layout — TOTAL ~214.1 MB < 258 MB proven-safe:
    //   h 51.2M | agg 51.2M | e8 102.4M (fp8, once) | wt 1.05M | csr 4.01M |
    //   ps 4.19M | small
    const size_t H_B = (size_t)NN * HIDC * 2;
    const size_t E8_B = (size_t)NE * HIDC;
    char* p = (char*)d_ws;
    bfu* hbuf = (bfu*)p; p += H_B;
    bfu* aggb = (bfu*)p; p += H_B;
    unsigned char* e8 = (unsigned char*)p; p += E8_B;
    bfu* wt = (bfu*)p; p += 8 * 65536 * 2;
    int* rowp = (int*)p;
    int* cursor = rowp + 100352;
    int* part = cursor + 100352;
    int* splits = part + 1024;
    int* cnts = splits + 8;
    int* csrc = cnts + 8;
    int* ceid = csrc + NE;
    p = (char*)(ceid + NE);
    float* psum = (float*)p; p += (size_t)NG * 8 * HIDC * 4;
    float* psq = (float*)p; p += (size_t)NG * 8 * HIDC * 4;
    char* small = p;
    int* starts = (int*)small;
    int* dtf = (int*)(small + 2048);
    float* weff = (float*)(small + 4096);       // 4x256 f32 = 4 KB
    float* beff = weff + 4 * HIDC;              // 256 f32 = 1 KB (ends < 16384)
    float* gmean = (float*)(small + 16384);
    float* gvar = gmean + NG * HIDC;
    float* gpool = gvar + NG * HIDC;
    (void)splits; (void)cnts;

    k_dt2<<<1, 64, 0, stream>>>((const unsigned int*)ngamma, dtf);
    k_st2<<<1, 512, 0, stream>>>(batch, starts);
    k_emb<<<(NN * 64 + 255) / 256, 256, 0, stream>>>(x, node_emb_W, hbuf, dtf);
    k_wef<<<5, 256, 0, stream>>>(edge_emb_W, edge_emb_b, emlp_W1, emlp_b1,
                                 weff, beff, dtf);

    k_wtr<<<256, 256, 0, stream>>>(emlp_W2, 0, wt + 65536, dtf);
    for (int l = 0; l < 3; ++l) {
        k_wtr<<<256, 256, 0, stream>>>(conv_W1, (long)l * HIDC * HIDC, wt + (2 + l) * 65536, dtf);
        k_wtr<<<256, 256, 0, stream>>>(conv_W2, (long)l * HIDC * HIDC, wt + (5 + l) * 65536, dtf);
    }

    const int NBN = (NN + 255) / 256;
    k_zi<<<NBN, 256, 0, stream>>>(cursor, NN);
    k_cnt<<<(NE + 255) / 256, 256, 0, stream>>>(ei, cursor);
    k_sc1<<<NBN, 256, 0, stream>>>(cursor, rowp, part);
    k_sc2<<<1, 64, 0, stream>>>(part, NBN);
    k_sc3<<<NBN, 256, 0, stream>>>(rowp, part);
    k_cpi<<<NBN, 256, 0, stream>>>(rowp, cursor, NN);
    k_fil<<<(NE + 255) / 256, 256, 0, stream>>>(ei, cursor, csrc, ceid);

    // e computed ONCE: e8 = fp8[(relu(attr@weff+beff) @ W2 + b2) * scale]
    dim3 gE((NE + 63) / 64), gN((NN + 63) / 64);
    k_me<<<gE, 512, 0, stream>>>(eattr, weff, beff, wt + 65536, emlp_b2,
                                 struct_scale, e8, dtf, ceid);

    dim3 gS1(NG, 8);
    const int gatBlocks = (NN * 32 + 255) / 256;

    for (int l = 0; l < 3; ++l) {
        k_gat4<<<gatBlocks, 256, 0, stream>>>(hbuf, e8, rowp, csrc, aggb);
        // fused conv: h = relu(((1+eps)h+agg)@W1+b1)@W2+b2, in-place on h
        k_cnv<<<gN, 256, 0, stream>>>(
            hbuf, aggb, conv_eps, l,
            wt + (2 + l) * 65536, conv_b1, (long)l * HIDC,
            wt + (5 + l) * 65536, conv_b2, (long)l * HIDC, dtf);
        k_s1<<<gS1, 256, 0, stream>>>(hbuf, starts, psum, psq);
        k_s2<<<NG, 256, 0, stream>>>(starts, psum, psq, nalpha, (long)l * HIDC,
                                     gmean, gvar, dtf);
        if (l < 2) {
            k_nrm<<<(NN * 64 + 255) / 256, 256, 0, stream>>>(
                hbuf, batch, gmean, gvar, ngamma, nbeta, nalpha, (long)l * HIDC, dtf);
        }
    }

    k_pl2<<<NG, 256, 0, stream>>>(starts, gmean, gvar, ngamma, nbeta, nalpha,
                                  (long)2 * HIDC, gpool, dtf);
    k_hd<<<NG, 256, 0, stream>>>(gpool, mean_bio, head_W1, head_b1,
                                 head_W2, head_b2, d_out, dtf);
}